// Round 10
// baseline (136.051 us; speedup 1.0000x reference)
//
#include <hip/hip_runtime.h>
#include <hip/hip_bf16.h>
#include <cstdint>

using f32x4  = __attribute__((ext_vector_type(4))) float;
using bf16x8 = __attribute__((ext_vector_type(8))) short;
typedef unsigned short u16;

#define B_DIM 64
#define N_DIM 1024
#define P_DIM 256
#define NTILE 8              // N / 128
#define NUPPER 36            // NTILE*(NTILE+1)/2
#define NB_PREP 16384        // (B*N)/4
#define NB_PAIR 2304         // B * NUPPER blocks (divisible by 8)
#define NB_GRAM 9216         // NB_PAIR * 4 wave partials

// RNE float->bf16
__device__ __forceinline__ u16 f2bf(float f) {
  uint32_t u = __float_as_uint(f);
  u += 0x7fffu + ((u >> 16) & 1u);
  return (u16)(u >> 16);
}

// ---------------------------------------------------------------------------
// Kernel 1: fused BCE partial + per-row sumsq + fp32->bf16 cast. (~HBM floor)
// ---------------------------------------------------------------------------
__global__ __launch_bounds__(256) void prep_kernel(
    const float* __restrict__ X, const float* __restrict__ T,
    u16* __restrict__ Xbf, float* __restrict__ sq,
    float* __restrict__ pb) {
  int tid  = threadIdx.x;
  int w    = tid >> 6, lane = tid & 63;
  size_t row = (size_t)blockIdx.x * 4 + w;
  const float4 xv = ((const float4*)(X + row * P_DIM))[lane];
  const float4 tv = ((const float4*)(T + row * P_DIM))[lane];
  float xs[4] = {xv.x, xv.y, xv.z, xv.w};
  float ts[4] = {tv.x, tv.y, tv.z, tv.w};
  float sqp = 0.f, bce = 0.f;
  ushort4 us;
  u16* up = (u16*)&us;
  #pragma unroll
  for (int i = 0; i < 4; ++i) {
    float x = xs[i];
    sqp += x * x;
    bce += fmaxf(x, 0.f) - x * ts[i] + __logf(1.f + __expf(-fabsf(x)));
    up[i] = f2bf(x);
  }
  ((ushort4*)(Xbf + row * P_DIM))[lane] = us;
  #pragma unroll
  for (int off = 32; off; off >>= 1) {
    sqp += __shfl_down(sqp, off);
    bce += __shfl_down(bce, off);
  }
  __shared__ float red[4];
  if (lane == 0) { sq[row] = sqp; red[w] = bce; }
  __syncthreads();
  if (tid == 0)
    pb[blockIdx.x] = red[0] + red[1] + red[2] + red[3];
}

// ---------------------------------------------------------------------------
// Kernel 2 (R10): register-direct Gram (R9 dataflow — global->reg->MFMA, no
// LDS, no barriers) repacked as 256-thread blocks = 4 DECOUPLED wave-tasks:
// the 4 quadrants of one (b,TI,TJ) tile pair (they share A/B row panels ->
// L1/L2 reuse). R9 post-mortem: single-wave workgroups don't pack (occupancy
// 28% despite VGPR=72 allowing 50%); per-wave serial L2 chains then dominate.
// 4-wave blocks remove the workgroup-slot cap; __launch_bounds__(256,4)
// budgets 128 VGPR (same occupancy step as 72, per m69) so the compiler can
// hoist next-step loads across the unrolled K-loop (ILP).
// ---------------------------------------------------------------------------
__global__ __launch_bounds__(256, 4) void gram_kernel(
    const u16* __restrict__ Xbf, const float* __restrict__ sq,
    float* __restrict__ pd) {
  // XCD-aware swizzle (NB_PAIR % 8 == 0): XCD x gets 288 consecutive logical
  // pair-ids = 8 batches -> panel set fits one L2.
  int p   = blockIdx.x;
  int blk = (p & 7) * (NB_PAIR / 8) + (p >> 3);
  int b   = blk / NUPPER;
  int pr  = blk - b * NUPPER;           // tile-pair 0..35
  int TI  = 0, t = pr;
  while (t >= NTILE - TI) { t -= NTILE - TI; ++TI; }
  int TJ = TI + t;                      // TJ >= TI
  const bool diag = (TI == TJ);

  int tid  = threadIdx.x;
  int w    = tid >> 6, lane = tid & 63; // wave = quadrant
  int wr   = w >> 1, wc = w & 1;
  if (diag && wr > wc) {                // dead quadrant: fully below diagonal
    if (lane == 0) pd[p * 4 + w] = 0.f;
    return;                             // no barriers anywhere -> safe
  }

  const u16*   Xb  = Xbf + (size_t)b * N_DIM * P_DIM;
  const float* sqb = sq + b * N_DIM;

  const int rowA = TI * 128 + wr * 64;
  const int rowB = TJ * 128 + wc * 64;
  const bool same = (rowA == rowB);     // diag (0,0)/(1,1): B tile == A tile

  // Fragment-direct pointers: lane reads row fr=lane&15 (+16m), 16B k-slot
  // ksl=lane>>4. Wave touches 16 fully-consumed 64B lines per load. Per-step
  // offset k*64B is a compile-time immediate under full unroll.
  const int fr = lane & 15, ksl = lane >> 4;
  const u16* pA0 = Xb + (size_t)(rowA + fr) * P_DIM + ksl * 8;
  const u16* pA1 = pA0 + 16 * P_DIM;
  const u16* pA2 = pA0 + 32 * P_DIM;
  const u16* pA3 = pA0 + 48 * P_DIM;
  const u16* pB0 = Xb + (size_t)(rowB + fr) * P_DIM + ksl * 8;
  const u16* pB1 = pB0 + 16 * P_DIM;
  const u16* pB2 = pB0 + 32 * P_DIM;
  const u16* pB3 = pB0 + 48 * P_DIM;

  f32x4 acc[4][4];
  #pragma unroll
  for (int m = 0; m < 4; ++m)
    #pragma unroll
    for (int n = 0; n < 4; ++n)
      acc[m][n] = (f32x4)(0.f);

  #pragma unroll
  for (int k = 0; k < 8; ++k) {
    const int off = k * 32;             // u16 elements = k*64 bytes
    bf16x8 a0 = *(const bf16x8*)(pA0 + off);
    bf16x8 a1 = *(const bf16x8*)(pA1 + off);
    bf16x8 a2 = *(const bf16x8*)(pA2 + off);
    bf16x8 a3 = *(const bf16x8*)(pA3 + off);
    bf16x8 b0, b1, b2, b3;
    if (!same) {
      b0 = *(const bf16x8*)(pB0 + off);
      b1 = *(const bf16x8*)(pB1 + off);
      b2 = *(const bf16x8*)(pB2 + off);
      b3 = *(const bf16x8*)(pB3 + off);
    } else {
      b0 = a0; b1 = a1; b2 = a2; b3 = a3;
    }
    acc[0][0] = __builtin_amdgcn_mfma_f32_16x16x32_bf16(a0, b0, acc[0][0], 0, 0, 0);
    acc[0][1] = __builtin_amdgcn_mfma_f32_16x16x32_bf16(a0, b1, acc[0][1], 0, 0, 0);
    acc[0][2] = __builtin_amdgcn_mfma_f32_16x16x32_bf16(a0, b2, acc[0][2], 0, 0, 0);
    acc[0][3] = __builtin_amdgcn_mfma_f32_16x16x32_bf16(a0, b3, acc[0][3], 0, 0, 0);
    acc[1][0] = __builtin_amdgcn_mfma_f32_16x16x32_bf16(a1, b0, acc[1][0], 0, 0, 0);
    acc[1][1] = __builtin_amdgcn_mfma_f32_16x16x32_bf16(a1, b1, acc[1][1], 0, 0, 0);
    acc[1][2] = __builtin_amdgcn_mfma_f32_16x16x32_bf16(a1, b2, acc[1][2], 0, 0, 0);
    acc[1][3] = __builtin_amdgcn_mfma_f32_16x16x32_bf16(a1, b3, acc[1][3], 0, 0, 0);
    acc[2][0] = __builtin_amdgcn_mfma_f32_16x16x32_bf16(a2, b0, acc[2][0], 0, 0, 0);
    acc[2][1] = __builtin_amdgcn_mfma_f32_16x16x32_bf16(a2, b1, acc[2][1], 0, 0, 0);
    acc[2][2] = __builtin_amdgcn_mfma_f32_16x16x32_bf16(a2, b2, acc[2][2], 0, 0, 0);
    acc[2][3] = __builtin_amdgcn_mfma_f32_16x16x32_bf16(a2, b3, acc[2][3], 0, 0, 0);
    acc[3][0] = __builtin_amdgcn_mfma_f32_16x16x32_bf16(a3, b0, acc[3][0], 0, 0, 0);
    acc[3][1] = __builtin_amdgcn_mfma_f32_16x16x32_bf16(a3, b1, acc[3][1], 0, 0, 0);
    acc[3][2] = __builtin_amdgcn_mfma_f32_16x16x32_bf16(a3, b2, acc[3][2], 0, 0, 0);
    acc[3][3] = __builtin_amdgcn_mfma_f32_16x16x32_bf16(a3, b3, acc[3][3], 0, 0, 0);
  }

  // Epilogue: C layout (m89/m91): col = lane&15, row = (lane>>4)*4 + v.
  float sqa[16], sqc[4];
  {
    int rb2 = rowA + (lane >> 4) * 4;
    int cb  = rowB + (lane & 15);
    #pragma unroll
    for (int m = 0; m < 4; ++m)
      #pragma unroll
      for (int v = 0; v < 4; ++v)
        sqa[m * 4 + v] = sqb[rb2 + m * 16 + v];
    #pragma unroll
    for (int n = 0; n < 4; ++n)
      sqc[n] = sqb[cb + n * 16];
  }
  float ssum = 0.f;
  #pragma unroll
  for (int m = 0; m < 4; ++m) {
    #pragma unroll
    for (int n = 0; n < 4; ++n) {
      #pragma unroll
      for (int v = 0; v < 4; ++v) {
        float d2 = sqa[m * 4 + v] + sqc[n] - 2.f * acc[m][n][v];
        float d  = sqrtf(fmaxf(d2, 0.f));
        if (same) {
          int li = m * 16 + (lane >> 4) * 4 + v;   // local row
          int lj = n * 16 + (lane & 15);           // local col
          d = (li < lj) ? d : 0.f;
        }
        ssum += d;
      }
    }
  }
  #pragma unroll
  for (int off = 32; off; off >>= 1) ssum += __shfl_down(ssum, off);
  if (lane == 0) pd[p * 4 + w] = ssum;
}

// ---------------------------------------------------------------------------
// Kernel 3: reduce partials (double) and combine.
// ---------------------------------------------------------------------------
__global__ __launch_bounds__(256) void finalize_kernel(
    const float* __restrict__ pb, const float* __restrict__ pd,
    float* __restrict__ out) {
  int tid = threadIdx.x;
  double s = 0.0, d = 0.0;
  for (int i = tid; i < NB_PREP; i += 256) s += (double)pb[i];
  for (int i = tid; i < NB_GRAM; i += 256) d += (double)pd[i];
  #pragma unroll
  for (int off = 32; off; off >>= 1) {
    s += __shfl_down(s, off);
    d += __shfl_down(d, off);
  }
  __shared__ double sb[4], db[4];
  int w = tid >> 6, lane = tid & 63;
  if (lane == 0) { sb[w] = s; db[w] = d; }
  __syncthreads();
  if (tid == 0) {
    double bce = (sb[0] + sb[1] + sb[2] + sb[3]) /
                 (double)((size_t)B_DIM * N_DIM * P_DIM);
    double reg = (db[0] + db[1] + db[2] + db[3]) / (double)N_DIM;
    out[0] = (float)(bce - reg);
  }
}

extern "C" void kernel_launch(void* const* d_in, const int* in_sizes, int n_in,
                              void* d_out, int out_size, void* d_ws, size_t ws_size,
                              hipStream_t stream) {
  const float* X = (const float*)d_in[0];
  const float* T = (const float*)d_in[1];
  float* out = (float*)d_out;

  // ws layout:
  //   [0, 64KB)        pb  — per-block BCE partials (16384 f32)
  //   [64KB, 100KB)    pd  — per-wave dist partials (9216 f32)
  //   [112KB, 368KB)   sq  — per-row sum of squares (65536 f32)
  //   [384KB, ~34MB)   Xbf — bf16 copy of X
  float* pb  = (float*)d_ws;
  float* pd  = (float*)((char*)d_ws + (64 << 10));
  float* sq  = (float*)((char*)d_ws + (112 << 10));
  u16*   Xbf = (u16*)  ((char*)d_ws + (384 << 10));

  prep_kernel<<<NB_PREP, 256, 0, stream>>>(X, T, Xbf, sq, pb);
  gram_kernel<<<NB_PAIR, 256, 0, stream>>>(Xbf, sq, pd);
  finalize_kernel<<<1, 256, 0, stream>>>(pb, pd, out);
}

// Round 11
// 100.706 us; speedup vs baseline: 1.3510x; 1.3510x over previous
//
#include <hip/hip_runtime.h>
#include <hip/hip_bf16.h>
#include <cstdint>

using f32x4  = __attribute__((ext_vector_type(4))) float;
using bf16x8 = __attribute__((ext_vector_type(8))) short;
typedef unsigned short u16;

#define B_DIM 64
#define N_DIM 1024
#define P_DIM 256
#define NB_PREP 16384        // (B*N)/4
#define NPAIR 10             // 4x4 256-tiles, upper-tri pairs per batch
#define NB_GRAM 640          // B * NPAIR (divisible by 8)
#define NPD (NB_GRAM * 8)    // per-wave partials

// RNE float->bf16
__device__ __forceinline__ u16 f2bf(float f) {
  uint32_t u = __float_as_uint(f);
  u += 0x7fffu + ((u >> 16) & 1u);
  return (u16)(u >> 16);
}

// ---------------------------------------------------------------------------
// Kernel 1: fused BCE partial + per-row sumsq + fp32->bf16 cast. (~HBM floor)
// ---------------------------------------------------------------------------
__global__ __launch_bounds__(256) void prep_kernel(
    const float* __restrict__ X, const float* __restrict__ T,
    u16* __restrict__ Xbf, float* __restrict__ sq,
    float* __restrict__ pb) {
  int tid  = threadIdx.x;
  int w    = tid >> 6, lane = tid & 63;
  size_t row = (size_t)blockIdx.x * 4 + w;
  const float4 xv = ((const float4*)(X + row * P_DIM))[lane];
  const float4 tv = ((const float4*)(T + row * P_DIM))[lane];
  float xs[4] = {xv.x, xv.y, xv.z, xv.w};
  float ts[4] = {tv.x, tv.y, tv.z, tv.w};
  float sqp = 0.f, bce = 0.f;
  ushort4 us;
  u16* up = (u16*)&us;
  #pragma unroll
  for (int i = 0; i < 4; ++i) {
    float x = xs[i];
    sqp += x * x;
    bce += fmaxf(x, 0.f) - x * ts[i] + __logf(1.f + __expf(-fabsf(x)));
    up[i] = f2bf(x);
  }
  ((ushort4*)(Xbf + row * P_DIM))[lane] = us;
  #pragma unroll
  for (int off = 32; off; off >>= 1) {
    sqp += __shfl_down(sqp, off);
    bce += __shfl_down(bce, off);
  }
  __shared__ float red[4];
  if (lane == 0) { sq[row] = sqp; red[w] = bce; }
  __syncthreads();
  if (tid == 0)
    pb[blockIdx.x] = red[0] + red[1] + red[2] + red[3];
}

// ---------------------------------------------------------------------------
// Kernel 2 (R11): 256x256 Gram tile. Rationale: ALL prior rounds (R2-R10,
// 65-133us) fit one model — ~590 MB staged through L2 at an achievable
// 6-9 TB/s. Quartering the staged bytes via 256^2 tiles (->~135 MB) attacks
// the binding constraint directly. 512 thr / 8 waves (2x4), per-wave 128x64
// sub-tile, BK=64, double-buffered 128KB LDS, ONE barrier per step.
// Reg-staging with R6/R7-verified both-sides XOR chunk swizzle (0 bank
// conflicts), NAMED stage registers (no arrays/lambdas — R4/R6 spill lesson),
// loads issued before compute (T14). XCD swizzle; diag pairs last, diag
// blocks skip B staging (B tile == A tile).
// ---------------------------------------------------------------------------
__global__ __launch_bounds__(512, 2) void gram_kernel(
    const u16* __restrict__ Xbf, const float* __restrict__ sq,
    float* __restrict__ pd) {
  __shared__ __align__(16) u16 As[2][256 * 64];   // 64 KB
  __shared__ __align__(16) u16 Bs[2][256 * 64];   // 64 KB

  // XCD swizzle (640 % 8 == 0): XCD x gets 80 consecutive logical ids
  // = 8 batches (their 256-row panels fit one L2).
  int p   = blockIdx.x;
  int blk = (p & 7) * (NB_GRAM / 8) + (p >> 3);
  int b   = blk / NPAIR;
  int pr  = blk - b * NPAIR;
  // pair order: 6 off-diag first, 4 diag last (cheap blocks in the tail)
  int TI, TJ;
  if (pr < 3)      { TI = 0;      TJ = pr + 1; }
  else if (pr < 5) { TI = 1;      TJ = pr - 1; }
  else if (pr < 6) { TI = 2;      TJ = 3;      }
  else             { TI = pr - 6; TJ = pr - 6; }
  const bool same = (TI == TJ);

  const u16*   Xb  = Xbf + (size_t)b * N_DIM * P_DIM;
  const float* sqb = sq + b * N_DIM;

  const int tid  = threadIdx.x;
  const int lane = tid & 63;
  const int w    = tid >> 6;            // 8 waves
  const int wr   = w >> 2, wc = w & 3;  // 2x4 grid; sub-tile 128x64
  const int rowA = TI * 256, rowB = TJ * 256;
  // dead waves on diag blocks: rows [128,256) vs cols [0,128) all i>j
  const bool live = !(same && wr == 1 && wc < 2);

  // ---- staging geometry: per matrix per step = 256 rows x 64 K = 32 KB =
  // 2048 chunks of 16B; thread covers chunks q*512+tid: r = sr+64q, s = tid&7.
  const int sr = tid >> 3;              // 0..63
  const int sp = (tid & 7) ^ (sr & 7);  // swizzled slot (const per thread)
  const u16* gA = Xb + (size_t)(rowA + sr) * P_DIM + (tid & 7) * 8;
  const u16* gB = Xb + (size_t)(rowB + sr) * P_DIM + (tid & 7) * 8;
  const int woff = sr * 64 + sp * 8;    // u16 units; + q*4096 per q
  #define GROWQ (64 * P_DIM)            // 64 rows in u16 units

  uint4 qa0, qa1, qa2, qa3, qb0, qb1, qb2, qb3;

#define LOAD_T(k0) do {                                           \
    qa0 = *(const uint4*)(gA + (k0));                             \
    qa1 = *(const uint4*)(gA + GROWQ + (k0));                     \
    qa2 = *(const uint4*)(gA + 2 * GROWQ + (k0));                 \
    qa3 = *(const uint4*)(gA + 3 * GROWQ + (k0));                 \
    if (!same) {                                                  \
      qb0 = *(const uint4*)(gB + (k0));                           \
      qb1 = *(const uint4*)(gB + GROWQ + (k0));                   \
      qb2 = *(const uint4*)(gB + 2 * GROWQ + (k0));               \
      qb3 = *(const uint4*)(gB + 3 * GROWQ + (k0));               \
    }                                                             \
  } while (0)

#define WRITE_T(buf) do {                                         \
    *(uint4*)&As[buf][woff]          = qa0;                       \
    *(uint4*)&As[buf][woff + 4096]   = qa1;                       \
    *(uint4*)&As[buf][woff + 8192]   = qa2;                       \
    *(uint4*)&As[buf][woff + 12288]  = qa3;                       \
    if (!same) {                                                  \
      *(uint4*)&Bs[buf][woff]         = qb0;                      \
      *(uint4*)&Bs[buf][woff + 4096]  = qb1;                      \
      *(uint4*)&Bs[buf][woff + 8192]  = qb2;                      \
      *(uint4*)&Bs[buf][woff + 12288] = qb3;                      \
    }                                                             \
  } while (0)

  // ---- read geometry: frag row = base + (lane&15), k-slot = kk*4+(lane>>4);
  // swizzled pos = slot ^ (row&7), row&7 == lane&7.
  const int h = lane & 15;
  const int rd0 = h * 64 + ((((lane >> 4)) ^ (lane & 7)) << 3);
  const int rd1 = h * 64 + (((4 + (lane >> 4)) ^ (lane & 7)) << 3);

  f32x4 acc[8][4];
  #pragma unroll
  for (int m = 0; m < 8; ++m)
    #pragma unroll
    for (int n = 0; n < 4; ++n)
      acc[m][n] = (f32x4)(0.f);

  LOAD_T(0);
  WRITE_T(0);
  __syncthreads();

  #pragma unroll
  for (int step = 0; step < 4; ++step) {
    const int cur = step & 1;
    if (step < 3) LOAD_T((step + 1) * 64);      // issue early (T14)
    if (live) {
      const u16* Ab = &As[cur][0];
      const u16* Bb = same ? Ab : &Bs[cur][0];
      const int abase = wr * 8192;              // (wr*128)*64
      const int bbase = wc * 4096;              // (wc*64)*64
      #pragma unroll
      for (int kk = 0; kk < 2; ++kk) {
        const int rd = kk ? rd1 : rd0;
        bf16x8 bfg[4];
        #pragma unroll
        for (int n = 0; n < 4; ++n)
          bfg[n] = *(const bf16x8*)&Bb[bbase + n * 1024 + rd];
        #pragma unroll
        for (int m = 0; m < 8; ++m) {
          bf16x8 af = *(const bf16x8*)&Ab[abase + m * 1024 + rd];
          #pragma unroll
          for (int n = 0; n < 4; ++n)
            acc[m][n] = __builtin_amdgcn_mfma_f32_16x16x32_bf16(
                af, bfg[n], acc[m][n], 0, 0, 0);
        }
      }
    }
    if (step < 3) WRITE_T(cur ^ 1);             // other buffer
    __syncthreads();
  }
#undef LOAD_T
#undef WRITE_T

  // Epilogue: C layout (m89/m91): col = lane&15, row = (lane>>4)*4 + v.
  float ssum = 0.f;
  if (live) {
    const int ksl = lane >> 4;
    #pragma unroll
    for (int m = 0; m < 8; ++m) {
      const int li0 = wr * 128 + m * 16 + ksl * 4;     // local row base
      #pragma unroll
      for (int v = 0; v < 4; ++v) {
        const float sqi = sqb[rowA + li0 + v];
        #pragma unroll
        for (int n = 0; n < 4; ++n) {
          const int lj = wc * 64 + n * 16 + h;          // local col
          float d2 = sqi + sqb[rowB + lj] - 2.f * acc[m][n][v];
          float d  = sqrtf(fmaxf(d2, 0.f));
          if (same) d = ((li0 + v) < lj) ? d : 0.f;
          ssum += d;
        }
      }
    }
  }
  #pragma unroll
  for (int off = 32; off; off >>= 1) ssum += __shfl_down(ssum, off);
  if (lane == 0) pd[p * 8 + w] = ssum;
}

// ---------------------------------------------------------------------------
// Kernel 3: reduce partials (double) and combine.
// ---------------------------------------------------------------------------
__global__ __launch_bounds__(256) void finalize_kernel(
    const float* __restrict__ pb, const float* __restrict__ pd,
    float* __restrict__ out) {
  int tid = threadIdx.x;
  double s = 0.0, d = 0.0;
  for (int i = tid; i < NB_PREP; i += 256) s += (double)pb[i];
  for (int i = tid; i < NPD; i += 256) d += (double)pd[i];
  #pragma unroll
  for (int off = 32; off; off >>= 1) {
    s += __shfl_down(s, off);
    d += __shfl_down(d, off);
  }
  __shared__ double sb[4], db[4];
  int w = tid >> 6, lane = tid & 63;
  if (lane == 0) { sb[w] = s; db[w] = d; }
  __syncthreads();
  if (tid == 0) {
    double bce = (sb[0] + sb[1] + sb[2] + sb[3]) /
                 (double)((size_t)B_DIM * N_DIM * P_DIM);
    double reg = (db[0] + db[1] + db[2] + db[3]) / (double)N_DIM;
    out[0] = (float)(bce - reg);
  }
}

extern "C" void kernel_launch(void* const* d_in, const int* in_sizes, int n_in,
                              void* d_out, int out_size, void* d_ws, size_t ws_size,
                              hipStream_t stream) {
  const float* X = (const float*)d_in[0];
  const float* T = (const float*)d_in[1];
  float* out = (float*)d_out;

  // ws layout:
  //   [0, 64KB)        pb  — per-block BCE partials (16384 f32)
  //   [64KB, 100KB)    pd  — per-wave dist partials (5120 f32)
  //   [112KB, 368KB)   sq  — per-row sum of squares (65536 f32)
  //   [384KB, ~34MB)   Xbf — bf16 copy of X
  float* pb  = (float*)d_ws;
  float* pd  = (float*)((char*)d_ws + (64 << 10));
  float* sq  = (float*)((char*)d_ws + (112 << 10));
  u16*   Xbf = (u16*)  ((char*)d_ws + (384 << 10));

  prep_kernel<<<NB_PREP, 256, 0, stream>>>(X, T, Xbf, sq, pb);
  gram_kernel<<<NB_GRAM, 512, 0, stream>>>(Xbf, sq, pd);
  finalize_kernel<<<1, 256, 0, stream>>>(pb, pd, out);
}

// Round 12
// 99.600 us; speedup vs baseline: 1.3660x; 1.0111x over previous
//
#include <hip/hip_runtime.h>
#include <hip/hip_bf16.h>
#include <cstdint>

using f32x4  = __attribute__((ext_vector_type(4))) float;
using bf16x8 = __attribute__((ext_vector_type(8))) short;
typedef unsigned short u16;

#define B_DIM 64
#define N_DIM 1024
#define P_DIM 256
#define NB_PREP 16384        // (B*N)/4
#define NB_GRAM 512          // 64 batches x 8 row-panels (divisible by 8)
#define NPD 2048             // 512 blocks x 4 waves

// RNE float->bf16
__device__ __forceinline__ u16 f2bf(float f) {
  uint32_t u = __float_as_uint(f);
  u += 0x7fffu + ((u >> 16) & 1u);
  return (u16)(u >> 16);
}

// ---------------------------------------------------------------------------
// Kernel 1: fused BCE partial + per-row sumsq + fp32->bf16 cast. (~HBM floor)
// ---------------------------------------------------------------------------
__global__ __launch_bounds__(256) void prep_kernel(
    const float* __restrict__ X, const float* __restrict__ T,
    u16* __restrict__ Xbf, float* __restrict__ sq,
    float* __restrict__ pb) {
  int tid  = threadIdx.x;
  int w    = tid >> 6, lane = tid & 63;
  size_t row = (size_t)blockIdx.x * 4 + w;
  const float4 xv = ((const float4*)(X + row * P_DIM))[lane];
  const float4 tv = ((const float4*)(T + row * P_DIM))[lane];
  float xs[4] = {xv.x, xv.y, xv.z, xv.w};
  float ts[4] = {tv.x, tv.y, tv.z, tv.w};
  float sqp = 0.f, bce = 0.f;
  ushort4 us;
  u16* up = (u16*)&us;
  #pragma unroll
  for (int i = 0; i < 4; ++i) {
    float x = xs[i];
    sqp += x * x;
    bce += fmaxf(x, 0.f) - x * ts[i] + __logf(1.f + __expf(-fabsf(x)));
    up[i] = f2bf(x);
  }
  ((ushort4*)(Xbf + row * P_DIM))[lane] = us;
  #pragma unroll
  for (int off = 32; off; off >>= 1) {
    sqp += __shfl_down(sqp, off);
    bce += __shfl_down(bce, off);
  }
  __shared__ float red[4];
  if (lane == 0) { sq[row] = sqp; red[w] = bce; }
  __syncthreads();
  if (tid == 0)
    pb[blockIdx.x] = red[0] + red[1] + red[2] + red[3];
}

// ---------------------------------------------------------------------------
// Kernel 2 (R12): resident-A deep-K Gram. Block = (batch, TI row-panel):
// stage A panel ONCE (128 rows x 256 K = 64 KB, XOR-swizzled), then sweep
// TJ = TI..7 streaming 8 KB B-chunks (BK=32, 2x8KB dbuf). K-depth per block
// up to 64 steps (vs 4-8 in R2-R11 — the invariant all failed rounds shared).
// LDS = exactly 80 KB -> 2 blocks/CU (barrier drains overlap, R7 property).
// Load-balanced XCD pairing: per XCD chunk, blocks 0-31 = heavy panels
// (TI 0..3), 32-63 = light (TI 7..4); round-robin dispatch pairs heavy[c] +
// light[c] on CU c -> 9 pair-units each. Diag TJ (first) reads B-frags from
// the resident A panel: no staging, no per-step barriers.
// Named stage regs (R6 spill lesson); 0-conflict XOR swizzle (R6-verified).
// ---------------------------------------------------------------------------
__global__ __launch_bounds__(256, 2) void gram_kernel(
    const u16* __restrict__ Xbf, const float* __restrict__ sq,
    float* __restrict__ pd) {
  __shared__ __align__(16) u16 Apan[128 * 256];   // 64 KB, resident
  __shared__ __align__(16) u16 Bs[2][128 * 32];   // 16 KB dbuf

  // Mapping: p&7 = XCD, l = p>>3 in [0,64): l<32 -> heavy (TI = l&3),
  // l>=32 -> light (TI = 7-(l&3)); batch = xcd*8 + ((l&31)>>2).
  const int p   = blockIdx.x;
  const int l   = p >> 3;
  const int b   = (p & 7) * 8 + ((l & 31) >> 2);
  const int TI  = (l < 32) ? (l & 3) : (7 - (l & 3));

  const u16*   Xb  = Xbf + (size_t)b * N_DIM * P_DIM;
  const float* sqb = sq + b * N_DIM;

  const int tid  = threadIdx.x;
  const int lane = tid & 63;
  const int w    = tid >> 6;            // 4 waves
  const int wr   = w >> 1, wc = w & 1;  // 2x2 over 128x128; 64x64 each
  const int rowA = TI * 128;

  // ---- A panel stage (once): 4096 16B chunks; thread covers (row, c) with
  // c = tid&31, row = gq*32 + {0,8,16,24} + (tid>>5); pos = c ^ (row&7),
  // row&7 == tid>>5 for all -> constant per thread.
  {
    const int c    = tid & 31;
    const int rb   = tid >> 5;                 // 0..7
    const int posA = c ^ rb;
    const u16* g   = Xb + (size_t)(rowA + rb) * P_DIM + c * 8;
    #pragma unroll
    for (int gq = 0; gq < 4; ++gq) {
      uint4 t0 = *(const uint4*)(g + (size_t)(gq * 32 +  0) * P_DIM);
      uint4 t1 = *(const uint4*)(g + (size_t)(gq * 32 +  8) * P_DIM);
      uint4 t2 = *(const uint4*)(g + (size_t)(gq * 32 + 16) * P_DIM);
      uint4 t3 = *(const uint4*)(g + (size_t)(gq * 32 + 24) * P_DIM);
      const int wo = (gq * 32 + rb) * 256 + posA * 8;
      *(uint4*)&Apan[wo]            = t0;
      *(uint4*)&Apan[wo +  8 * 256] = t1;
      *(uint4*)&Apan[wo + 16 * 256] = t2;
      *(uint4*)&Apan[wo + 24 * 256] = t3;
    }
  }
  __syncthreads();

  const int h = lane & 15, ksl = lane >> 4;
  const int aRowBase  = (wr * 64 + h) * 256;   // + m*4096 + cpos(step)
  const int bRowBaseA = (wc * 64 + h) * 256;   // diag: B-frags from Apan
  const int bOffBs    = (wc * 64 + h) * 32 + ((ksl ^ ((h >> 1) & 3)) << 3);

  // B staging geometry (R6-verified 0-conflict scheme): r = q*64 + tid>>2,
  // s = tid&3; pos = s ^ ((tid>>3)&3) (independent of q).
  const int sB    = tid & 3;
  const int woffB = (tid >> 2) * 32 + ((sB ^ ((tid >> 3) & 3)) << 3);

  // Epilogue A-side sq (TJ-invariant)
  float sqa[16];
  {
    const int gi0 = rowA + wr * 64 + ksl * 4;
    #pragma unroll
    for (int m = 0; m < 4; ++m)
      #pragma unroll
      for (int v = 0; v < 4; ++v)
        sqa[m * 4 + v] = sqb[gi0 + m * 16 + v];
  }

  float ssum = 0.f;

  for (int TJ = TI; TJ < 8; ++TJ) {
    const bool same = (TJ == TI);               // first iteration only
    const int rowB  = TJ * 128;
    const bool live = !(same && wr == 1 && wc == 0);

    f32x4 acc[4][4];
    #pragma unroll
    for (int m = 0; m < 4; ++m)
      #pragma unroll
      for (int n = 0; n < 4; ++n)
        acc[m][n] = (f32x4)(0.f);

    const u16* gBq0 = Xb + (size_t)(rowB + (tid >> 2)) * P_DIM + sB * 8;
    const u16* gBq1 = gBq0 + (size_t)64 * P_DIM;
    uint4 qb0, qb1;

    if (!same) {                                // prologue: chunk 0 -> buf 0
      qb0 = *(const uint4*)(gBq0);
      qb1 = *(const uint4*)(gBq1);
      *(uint4*)&Bs[0][woffB]        = qb0;
      *(uint4*)&Bs[0][woffB + 2048] = qb1;
      __syncthreads();
    }

    #pragma unroll
    for (int step = 0; step < 8; ++step) {
      const int cur = step & 1;
      if (!same && step < 7) {                  // T14: issue early
        qb0 = *(const uint4*)(gBq0 + (step + 1) * 32);
        qb1 = *(const uint4*)(gBq1 + (step + 1) * 32);
      }
      if (live) {
        const int cpos = (((step * 4 + ksl) ^ (h & 7)) << 3);
        bf16x8 af0 = *(const bf16x8*)&Apan[aRowBase          + cpos];
        bf16x8 af1 = *(const bf16x8*)&Apan[aRowBase +  4096  + cpos];
        bf16x8 af2 = *(const bf16x8*)&Apan[aRowBase +  8192  + cpos];
        bf16x8 af3 = *(const bf16x8*)&Apan[aRowBase + 12288  + cpos];
        bf16x8 bf0, bf1, bf2, bf3;
        if (same) {
          bf0 = *(const bf16x8*)&Apan[bRowBaseA          + cpos];
          bf1 = *(const bf16x8*)&Apan[bRowBaseA +  4096  + cpos];
          bf2 = *(const bf16x8*)&Apan[bRowBaseA +  8192  + cpos];
          bf3 = *(const bf16x8*)&Apan[bRowBaseA + 12288  + cpos];
        } else {
          const u16* Bb = &Bs[cur][0];
          bf0 = *(const bf16x8*)&Bb[bOffBs];
          bf1 = *(const bf16x8*)&Bb[bOffBs +  512];
          bf2 = *(const bf16x8*)&Bb[bOffBs + 1024];
          bf3 = *(const bf16x8*)&Bb[bOffBs + 1536];
        }
        acc[0][0] = __builtin_amdgcn_mfma_f32_16x16x32_bf16(af0, bf0, acc[0][0], 0, 0, 0);
        acc[0][1] = __builtin_amdgcn_mfma_f32_16x16x32_bf16(af0, bf1, acc[0][1], 0, 0, 0);
        acc[0][2] = __builtin_amdgcn_mfma_f32_16x16x32_bf16(af0, bf2, acc[0][2], 0, 0, 0);
        acc[0][3] = __builtin_amdgcn_mfma_f32_16x16x32_bf16(af0, bf3, acc[0][3], 0, 0, 0);
        acc[1][0] = __builtin_amdgcn_mfma_f32_16x16x32_bf16(af1, bf0, acc[1][0], 0, 0, 0);
        acc[1][1] = __builtin_amdgcn_mfma_f32_16x16x32_bf16(af1, bf1, acc[1][1], 0, 0, 0);
        acc[1][2] = __builtin_amdgcn_mfma_f32_16x16x32_bf16(af1, bf2, acc[1][2], 0, 0, 0);
        acc[1][3] = __builtin_amdgcn_mfma_f32_16x16x32_bf16(af1, bf3, acc[1][3], 0, 0, 0);
        acc[2][0] = __builtin_amdgcn_mfma_f32_16x16x32_bf16(af2, bf0, acc[2][0], 0, 0, 0);
        acc[2][1] = __builtin_amdgcn_mfma_f32_16x16x32_bf16(af2, bf1, acc[2][1], 0, 0, 0);
        acc[2][2] = __builtin_amdgcn_mfma_f32_16x16x32_bf16(af2, bf2, acc[2][2], 0, 0, 0);
        acc[2][3] = __builtin_amdgcn_mfma_f32_16x16x32_bf16(af2, bf3, acc[2][3], 0, 0, 0);
        acc[3][0] = __builtin_amdgcn_mfma_f32_16x16x32_bf16(af3, bf0, acc[3][0], 0, 0, 0);
        acc[3][1] = __builtin_amdgcn_mfma_f32_16x16x32_bf16(af3, bf1, acc[3][1], 0, 0, 0);
        acc[3][2] = __builtin_amdgcn_mfma_f32_16x16x32_bf16(af3, bf2, acc[3][2], 0, 0, 0);
        acc[3][3] = __builtin_amdgcn_mfma_f32_16x16x32_bf16(af3, bf3, acc[3][3], 0, 0, 0);
      }
      if (!same && step < 7) {                  // write other buffer
        *(uint4*)&Bs[cur ^ 1][woffB]        = qb0;
        *(uint4*)&Bs[cur ^ 1][woffB + 2048] = qb1;
      }
      if (!same) __syncthreads();               // diag steps need no barrier
    }

    // Per-TJ epilogue: C layout (m89/m91) col = h, row = ksl*4 + v.
    if (live) {
      #pragma unroll
      for (int n = 0; n < 4; ++n) {
        const int lj = wc * 64 + n * 16 + h;    // local col in 128-tile
        const float sqc = sqb[rowB + lj];
        #pragma unroll
        for (int m = 0; m < 4; ++m) {
          const int li0 = wr * 64 + m * 16 + ksl * 4;
          #pragma unroll
          for (int v = 0; v < 4; ++v) {
            float d2 = sqa[m * 4 + v] + sqc - 2.f * acc[m][n][v];
            float d  = sqrtf(fmaxf(d2, 0.f));
            if (same) d = ((li0 + v) < lj) ? d : 0.f;
            ssum += d;
          }
        }
      }
    }
  }

  #pragma unroll
  for (int off = 32; off; off >>= 1) ssum += __shfl_down(ssum, off);
  if (lane == 0) pd[p * 4 + w] = ssum;
}

// ---------------------------------------------------------------------------
// Kernel 3: reduce partials (double) and combine.
// ---------------------------------------------------------------------------
__global__ __launch_bounds__(256) void finalize_kernel(
    const float* __restrict__ pb, const float* __restrict__ pd,
    float* __restrict__ out) {
  int tid = threadIdx.x;
  double s = 0.0, d = 0.0;
  for (int i = tid; i < NB_PREP; i += 256) s += (double)pb[i];
  for (int i = tid; i < NPD; i += 256) d += (double)pd[i];
  #pragma unroll
  for (int off = 32; off; off >>= 1) {
    s += __shfl_down(s, off);
    d += __shfl_down(d, off);
  }
  __shared__ double sb[4], db[4];
  int w = tid >> 6, lane = tid & 63;
  if (lane == 0) { sb[w] = s; db[w] = d; }
  __syncthreads();
  if (tid == 0) {
    double bce = (sb[0] + sb[1] + sb[2] + sb[3]) /
                 (double)((size_t)B_DIM * N_DIM * P_DIM);
    double reg = (db[0] + db[1] + db[2] + db[3]) / (double)N_DIM;
    out[0] = (float)(bce - reg);
  }
}

extern "C" void kernel_launch(void* const* d_in, const int* in_sizes, int n_in,
                              void* d_out, int out_size, void* d_ws, size_t ws_size,
                              hipStream_t stream) {
  const float* X = (const float*)d_in[0];
  const float* T = (const float*)d_in[1];
  float* out = (float*)d_out;

  // ws layout:
  //   [0, 64KB)        pb  — per-block BCE partials (16384 f32)
  //   [64KB, 72KB)     pd  — per-wave dist partials (2048 f32)
  //   [112KB, 368KB)   sq  — per-row sum of squares (65536 f32)
  //   [384KB, ~34MB)   Xbf — bf16 copy of X
  float* pb  = (float*)d_ws;
  float* pd  = (float*)((char*)d_ws + (64 << 10));
  float* sq  = (float*)((char*)d_ws + (112 << 10));
  u16*   Xbf = (u16*)  ((char*)d_ws + (384 << 10));

  prep_kernel<<<NB_PREP, 256, 0, stream>>>(X, T, Xbf, sq, pb);
  gram_kernel<<<NB_GRAM, 256, 0, stream>>>(Xbf, sq, pd);
  finalize_kernel<<<1, 256, 0, stream>>>(pb, pd, out);
}